// Round 1
// baseline (1169.881 us; speedup 1.0000x reference)
//
#include <hip/hip_runtime.h>

typedef unsigned short u16;
typedef unsigned int u32;

#define BB 64
#define FF 4096
#define DD 192
#define HH 768

typedef __attribute__((ext_vector_type(8))) __bf16 bf16x8;
typedef __attribute__((ext_vector_type(4))) float f32x4;

__device__ __forceinline__ float bf2f(u16 u) {
  union { u32 i; float f; } x; x.i = ((u32)u) << 16; return x.f;
}
__device__ __forceinline__ u16 f2bf(float f) {
  union { u32 i; float f; } x; x.f = f;
  return (u16)((x.i + 0x7fffu + ((x.i >> 16) & 1u)) >> 16);
}

// ---------------------------------------------------------------------------
// Prep: WmodT[n][e] = g[e]*W[e][n] (bf16, n<192 -> Wk, else Wv), s1[n]=sum g*W,
// s0[n]=sum b*W.
// ---------------------------------------------------------------------------
__global__ void prep_wmod(const float* __restrict__ Wk, const float* __restrict__ Wv,
                          const float* __restrict__ g, const float* __restrict__ bb,
                          u16* __restrict__ wmodT, float* __restrict__ s1,
                          float* __restrict__ s0) {
  int n = threadIdx.x;  // 0..383
  const float* W = (n < DD) ? Wk : Wv;
  int col = (n < DD) ? n : n - DD;
  float a1 = 0.f, a0 = 0.f;
  for (int e = 0; e < DD; ++e) {
    float w = W[e * DD + col];
    u16 h = f2bf(g[e] * w);
    wmodT[n * DD + e] = h;
    a1 += bf2f(h);
    a0 += bb[e] * w;
  }
  s1[n] = a1; s0[n] = a0;
}

// Transpose GRU weights: (576,192) -> (192,576) per group, both Wih and Whh.
__global__ void prep_grut(const float* __restrict__ Wih, const float* __restrict__ Whh,
                          float* __restrict__ WihT, float* __restrict__ WhhT) {
  int gsel = blockIdx.x;           // 0..5
  int g = gsel % 3;
  const float* src = (gsel < 3) ? (Wih + g * 576 * DD) : (Whh + g * 576 * DD);
  float* dst = (gsel < 3) ? (WihT + g * 576 * DD) : (WhhT + g * 576 * DD);
  for (int idx = threadIdx.x; idx < 576 * DD; idx += blockDim.x) {
    int e = idx / 576, n = idx % 576;
    dst[idx] = src[n * DD + e];
  }
}

// ---------------------------------------------------------------------------
// Projection: k = LN(x)@Wk, v = LN(x)@Wv, LN folded into epilogue.
// kbuf: token-major (B*F,192) bf16.  vT: d-major (B,192,F) bf16.
// Block: 512 thr (8 waves), M-tile = 128 tokens, N = 384 (k|v).
// ---------------------------------------------------------------------------
__global__ __launch_bounds__(512) void proj_kernel(
    const float* __restrict__ feat, const u16* __restrict__ wmodT,
    const float* __restrict__ s1, const float* __restrict__ s0,
    u16* __restrict__ kbuf, u16* __restrict__ vT) {
  __shared__ __align__(16) u16 Atile[128 * 192];  // swizzled bf16
  __shared__ float stats[256];                    // (sum,sumsq) -> (mu,rstd)
  int tid = threadIdx.x;
  long tile_base = (long)blockIdx.x * 128;
  if (tid < 256) stats[tid] = 0.f;
  __syncthreads();
  const float4* src = (const float4*)(feat + tile_base * DD);
  #pragma unroll
  for (int i = 0; i < 12; ++i) {
    int idx = tid + i * 512;        // 6144 float4 per tile, 48 per row
    float4 v = src[idx];
    int row = idx / 48, fc = idx % 48;
    atomicAdd(&stats[row * 2], v.x + v.y + v.z + v.w);
    atomicAdd(&stats[row * 2 + 1], v.x * v.x + v.y * v.y + v.z * v.z + v.w * v.w);
    uint2 p;
    p.x = (u32)f2bf(v.x) | ((u32)f2bf(v.y) << 16);
    p.y = (u32)f2bf(v.z) | ((u32)f2bf(v.w) << 16);
    int u = fc >> 1, half = fc & 1;
    int byteoff = row * 384 + ((u ^ (row & 7)) << 4) + (half << 3);
    *(uint2*)((char*)Atile + byteoff) = p;
  }
  __syncthreads();
  if (tid < 128) {
    float s = stats[tid * 2], s2 = stats[tid * 2 + 1];
    float mu = s * (1.f / 192.f);
    float var = s2 * (1.f / 192.f) - mu * mu;
    stats[tid * 2] = mu;
    stats[tid * 2 + 1] = rsqrtf(var + 1e-5f);
  }
  __syncthreads();
  int w = tid >> 6, lane = tid & 63;
  int mh = w >> 2, nq = w & 3;     // M-half (64 rows), N-quarter (96 cols)
  int l15 = lane & 15, l4 = lane >> 4;
  f32x4 acc[4][6];
  #pragma unroll
  for (int a = 0; a < 4; ++a)
    #pragma unroll
    for (int b2 = 0; b2 < 6; ++b2) acc[a][b2] = (f32x4){0.f, 0.f, 0.f, 0.f};
  #pragma unroll
  for (int kk = 0; kk < 6; ++kk) {
    bf16x8 afr[4];
    #pragma unroll
    for (int mt = 0; mt < 4; ++mt) {
      int row = mh * 64 + mt * 16 + l15;
      int u = kk * 4 + l4;
      afr[mt] = *(bf16x8*)((char*)Atile + row * 384 + ((u ^ (row & 7)) << 4));
    }
    bf16x8 bfr[6];
    #pragma unroll
    for (int nt = 0; nt < 6; ++nt) {
      int col = nq * 96 + nt * 16 + l15;
      bfr[nt] = *(const bf16x8*)(wmodT + col * DD + kk * 32 + l4 * 8);
    }
    #pragma unroll
    for (int mt = 0; mt < 4; ++mt)
      #pragma unroll
      for (int nt = 0; nt < 6; ++nt)
        acc[mt][nt] = __builtin_amdgcn_mfma_f32_16x16x32_bf16(afr[mt], bfr[nt],
                                                              acc[mt][nt], 0, 0, 0);
  }
  long bidx = tile_base / FF;
  int f0 = (int)(tile_base % FF);
  #pragma unroll
  for (int nt = 0; nt < 6; ++nt) {
    int col = nq * 96 + nt * 16 + l15;
    float s1c = s1[col], s0c = s0[col];
    #pragma unroll
    for (int mt = 0; mt < 4; ++mt) {
      int row0 = mh * 64 + mt * 16 + l4 * 4;
      if (nq < 2) {  // k: token-major scatter (2B stores, L2 write-combines)
        #pragma unroll
        for (int j = 0; j < 4; ++j) {
          int row = row0 + j;
          float mu = stats[row * 2], rstd = stats[row * 2 + 1];
          kbuf[(tile_base + row) * DD + col] = f2bf(rstd * (acc[mt][nt][j] - mu * s1c) + s0c);
        }
      } else {       // v: d-major, 4 consecutive tokens pack into one 8B store
        u16 h[4];
        #pragma unroll
        for (int j = 0; j < 4; ++j) {
          int row = row0 + j;
          float mu = stats[row * 2], rstd = stats[row * 2 + 1];
          h[j] = f2bf(rstd * (acc[mt][nt][j] - mu * s1c) + s0c);
        }
        uint2 p;
        p.x = (u32)h[0] | ((u32)h[1] << 16);
        p.y = (u32)h[2] | ((u32)h[3] << 16);
        *(uint2*)(vT + (bidx * 192 + (col - 192)) * FF + f0 + row0) = p;
      }
    }
  }
}

// ---------------------------------------------------------------------------
// q projection: q = LN(slots) @ Wq * scale.  One wave per (b,k).
// ---------------------------------------------------------------------------
__global__ __launch_bounds__(64) void qproj_kernel(
    const float* __restrict__ slots, const float* __restrict__ Wq,
    const float* __restrict__ g, const float* __restrict__ bb,
    float* __restrict__ qbuf) {
  __shared__ float ln[192];
  int bk = blockIdx.x;
  int lane = threadIdx.x;
  const float* x = slots + bk * DD;
  float v0 = x[lane], v1 = x[lane + 64], v2 = x[lane + 128];
  float s = v0 + v1 + v2, s2 = v0 * v0 + v1 * v1 + v2 * v2;
  #pragma unroll
  for (int m = 1; m < 64; m <<= 1) { s += __shfl_xor(s, m); s2 += __shfl_xor(s2, m); }
  float mu = s * (1.f / 192.f);
  float rstd = rsqrtf(s2 * (1.f / 192.f) - mu * mu + 1e-5f);
  ln[lane]       = (v0 - mu) * rstd * g[lane]       + bb[lane];
  ln[lane + 64]  = (v1 - mu) * rstd * g[lane + 64]  + bb[lane + 64];
  ln[lane + 128] = (v2 - mu) * rstd * g[lane + 128] + bb[lane + 128];
  __syncthreads();
  float a0 = 0.f, a1 = 0.f, a2 = 0.f;
  for (int e = 0; e < DD; ++e) {
    float le = ln[e];
    a0 += le * Wq[e * DD + lane];
    a1 += le * Wq[e * DD + lane + 64];
    a2 += le * Wq[e * DD + lane + 128];
  }
  const float scale = 0.07216878364870323f;  // 192^-0.5
  qbuf[bk * DD + lane]       = a0 * scale;
  qbuf[bk * DD + lane + 64]  = a1 * scale;
  qbuf[bk * DD + lane + 128] = a2 * scale;
}

// ---------------------------------------------------------------------------
// Attention: dots = q@k^T (+ spatial bias), softmax over 8 slots, store attn
// (slot-major bf16), accumulate attn sums + coord moments.
// C[slot][token] via mfma: A=q (LDS, swizzled, rows 8..15 zero), B=k (global).
// ---------------------------------------------------------------------------
__global__ __launch_bounds__(256) void attn_kernel(
    const u16* __restrict__ kbuf, const float* __restrict__ qbuf,
    const float* __restrict__ asum_prev, const float* __restrict__ cacc_prev,
    u16* __restrict__ attnT, float* __restrict__ asum_cur,
    float* __restrict__ cacc_cur, int have_bias) {
  __shared__ __align__(16) u16 qlds[16 * 192];
  int b = blockIdx.x;
  int chunk = blockIdx.y * 1024;
  int tid = threadIdx.x;
  if (tid < 192) {
    int s = tid / 24, u = tid % 24;
    const float* qp = qbuf + (b * 8 + s) * DD + u * 8;
    uint4 p;
    p.x = (u32)f2bf(qp[0]) | ((u32)f2bf(qp[1]) << 16);
    p.y = (u32)f2bf(qp[2]) | ((u32)f2bf(qp[3]) << 16);
    p.z = (u32)f2bf(qp[4]) | ((u32)f2bf(qp[5]) << 16);
    p.w = (u32)f2bf(qp[6]) | ((u32)f2bf(qp[7]) << 16);
    *(uint4*)((char*)qlds + s * 384 + ((u ^ (s & 7)) << 4)) = p;
  } else {
    int t2 = tid - 192;
    #pragma unroll
    for (int i = 0; i < 3; ++i) {
      int idx = t2 * 3 + i;      // 192 units of rows 8..15
      int s = 8 + idx / 24, u = idx % 24;
      *(uint4*)((char*)qlds + s * 384 + ((u ^ (s & 7)) << 4)) = (uint4){0, 0, 0, 0};
    }
  }
  __syncthreads();
  int w = tid >> 6, lane = tid & 63;
  int l15 = lane & 15, l4 = lane >> 4;
  bf16x8 qfr[6];
  #pragma unroll
  for (int kk = 0; kk < 6; ++kk) {
    int u = kk * 4 + l4;
    qfr[kk] = *(bf16x8*)((char*)qlds + l15 * 384 + ((u ^ (l15 & 7)) << 4));
  }
  float ax[4], ay[4], c0[4];
  #pragma unroll
  for (int j = 0; j < 4; ++j) {
    int s = l4 * 4 + j;
    if (have_bias && s < 8) {
      float inv = 1.f / (asum_prev[b * 8 + s] + 1e-8f);
      float cx = cacc_prev[(b * 8 + s) * 2] * inv;
      float cy = cacc_prev[(b * 8 + s) * 2 + 1] * inv;
      ax[j] = 16.f * cx; ay[j] = 16.f * cy; c0[j] = -8.f * (cx * cx + cy * cy);
    } else { ax[j] = 0.f; ay[j] = 0.f; c0[j] = 0.f; }
  }
  float pa[4], px[4], py[4];
  #pragma unroll
  for (int j = 0; j < 4; ++j) { pa[j] = 0.f; px[j] = 0.f; py[j] = 0.f; }
  for (int tile = w; tile < 64; tile += 4) {
    int t0 = chunk + tile * 16;
    const u16* kp = kbuf + ((long)(b * FF + t0 + l15)) * DD + l4 * 8;
    f32x4 acc = (f32x4){0.f, 0.f, 0.f, 0.f};
    #pragma unroll
    for (int kk = 0; kk < 6; ++kk) {
      bf16x8 bfr = *(const bf16x8*)(kp + kk * 32);
      acc = __builtin_amdgcn_mfma_f32_16x16x32_bf16(qfr[kk], bfr, acc, 0, 0, 0);
    }
    int t = t0 + l15;
    float x = -1.f + (float)(t & 63) * (2.f / 63.f);
    float y = -1.f + (float)(t >> 6) * (2.f / 63.f);
    float m8r2 = -8.f * (x * x + y * y);
    float d4[4];
    #pragma unroll
    for (int j = 0; j < 4; ++j)
      d4[j] = acc[j] + (have_bias ? (ax[j] * x + ay[j] * y + c0[j] + m8r2) : 0.f);
    float o4[4];
    #pragma unroll
    for (int j = 0; j < 4; ++j) o4[j] = __shfl_xor(d4[j], 16);
    float mx = fmaxf(fmaxf(fmaxf(d4[0], d4[1]), fmaxf(d4[2], d4[3])),
                     fmaxf(fmaxf(o4[0], o4[1]), fmaxf(o4[2], o4[3])));
    float e4[4];
    float sum = 0.f;
    #pragma unroll
    for (int j = 0; j < 4; ++j) { e4[j] = __expf(d4[j] - mx); sum += e4[j]; }
    #pragma unroll
    for (int j = 0; j < 4; ++j) sum += __expf(o4[j] - mx);
    float inv = 1.f / sum;
    if (l4 < 2) {
      #pragma unroll
      for (int j = 0; j < 4; ++j) {
        float a = e4[j] * inv;
        attnT[((long)(b * 16) + l4 * 4 + j) * FF + t] = f2bf(a);
        pa[j] += a; px[j] += a * x; py[j] += a * y;
      }
    }
  }
  #pragma unroll
  for (int m = 1; m < 16; m <<= 1) {
    #pragma unroll
    for (int j = 0; j < 4; ++j) {
      pa[j] += __shfl_xor(pa[j], m);
      px[j] += __shfl_xor(px[j], m);
      py[j] += __shfl_xor(py[j], m);
    }
  }
  if (l15 == 0 && l4 < 2) {
    #pragma unroll
    for (int j = 0; j < 4; ++j) {
      int s = l4 * 4 + j;
      atomicAdd(&asum_cur[b * 8 + s], pa[j]);
      atomicAdd(&cacc_cur[(b * 8 + s) * 2], px[j]);
      atomicAdd(&cacc_cur[(b * 8 + s) * 2 + 1], py[j]);
    }
  }
}

// ---------------------------------------------------------------------------
// updates (unnormalized) = attn @ v.  C[slot][d] via mfma:
// A = attnT (slot-major), B = vT (d-major).  grid (B, 12 n-tiles), 4 waves=K-chunks.
// ---------------------------------------------------------------------------
__global__ __launch_bounds__(256) void upd_kernel(
    const u16* __restrict__ attnT, const u16* __restrict__ vT,
    float* __restrict__ upd) {
  int b = blockIdx.x, nt = blockIdx.y;
  int tid = threadIdx.x;
  int w = tid >> 6, lane = tid & 63;
  int l15 = lane & 15, l4 = lane >> 4;
  int kc = w * 1024;
  const u16* ap = attnT + ((long)(b * 16) + l15) * FF + kc + l4 * 8;
  const u16* vp = vT + ((long)b * 192 + nt * 16 + l15) * FF + kc + l4 * 8;
  f32x4 acc = (f32x4){0.f, 0.f, 0.f, 0.f};
  #pragma unroll 4
  for (int ks = 0; ks < 32; ++ks) {
    bf16x8 afr = *(const bf16x8*)(ap + ks * 32);
    bf16x8 bfr = *(const bf16x8*)(vp + ks * 32);
    acc = __builtin_amdgcn_mfma_f32_16x16x32_bf16(afr, bfr, acc, 0, 0, 0);
  }
  if (l4 < 2) {
    #pragma unroll
    for (int j = 0; j < 4; ++j) {
      int s = l4 * 4 + j;
      atomicAdd(&upd[(b * 8 + s) * DD + nt * 16 + l15], acc[j]);
    }
  }
}

// ---------------------------------------------------------------------------
// GRU + LN + MLP, one block per (b, slot-subgroup).  192 threads.
// ---------------------------------------------------------------------------
template <int M>
__device__ void gru_body(int b, int g, int s0f, float* smem,
                         const float* __restrict__ upd, const float* __restrict__ asum,
                         const float* __restrict__ sin_,
                         const float* __restrict__ WihT, const float* __restrict__ WhhT,
                         const float* __restrict__ bih, const float* __restrict__ bhh,
                         const float* __restrict__ mlng, const float* __restrict__ mlnb,
                         const float* __restrict__ W1, const float* __restrict__ b1,
                         const float* __restrict__ W2, const float* __restrict__ b2,
                         float* __restrict__ sout) {
  float* u_l  = smem;          // [3][192]
  float* h_l  = smem + 576;
  float* h2_l = smem + 1152;
  float* ln_l = smem + 1728;
  float* x1_l = smem + 2304;   // [3][768]
  float* st   = smem + 4608;   // [3][2]
  int d = threadIdx.x;
  const float* WihTg = WihT + g * DD * 576;
  const float* WhhTg = WhhT + g * DD * 576;
  #pragma unroll
  for (int j = 0; j < M; ++j) {
    int row = b * 8 + s0f + j;
    float inv = 1.f / (asum[row] + 1e-8f);
    u_l[j * 192 + d] = upd[row * DD + d] * inv;
    h_l[j * 192 + d] = sin_[row * DD + d];
  }
  __syncthreads();
  float air[M], aiz[M], ain[M], ahr[M], ahz[M], ahn[M];
  #pragma unroll
  for (int j = 0; j < M; ++j) { air[j]=0.f; aiz[j]=0.f; ain[j]=0.f; ahr[j]=0.f; ahz[j]=0.f; ahn[j]=0.f; }
  #pragma unroll 2
  for (int e = 0; e < DD; ++e) {
    float wir = WihTg[e * 576 + d];
    float wiz = WihTg[e * 576 + 192 + d];
    float win = WihTg[e * 576 + 384 + d];
    float whr = WhhTg[e * 576 + d];
    float whz = WhhTg[e * 576 + 192 + d];
    float whn = WhhTg[e * 576 + 384 + d];
    #pragma unroll
    for (int j = 0; j < M; ++j) {
      float ue = u_l[j * 192 + e], he = h_l[j * 192 + e];
      air[j] += wir * ue; aiz[j] += wiz * ue; ain[j] += win * ue;
      ahr[j] += whr * he; ahz[j] += whz * he; ahn[j] += whn * he;
    }
  }
  const float* bihg = bih + g * 576;
  const float* bhhg = bhh + g * 576;
  float bir = bihg[d], biz = bihg[192 + d], bin = bihg[384 + d];
  float bhr = bhhg[d], bhz = bhhg[192 + d], bhn = bhhg[384 + d];
  float hnew[M];
  #pragma unroll
  for (int j = 0; j < M; ++j) {
    float r = 1.f / (1.f + __expf(-(air[j] + bir + ahr[j] + bhr)));
    float z = 1.f / (1.f + __expf(-(aiz[j] + biz + ahz[j] + bhz)));
    float nn = ain[j] + bin + r * (ahn[j] + bhn);
    float t = 1.f - 2.f / (__expf(2.f * nn) + 1.f);  // tanh
    float h = (1.f - z) * t + z * h_l[j * 192 + d];
    hnew[j] = h;
    h2_l[j * 192 + d] = h;
  }
  __syncthreads();
  int wv = d >> 6, lane = d & 63;
  if (wv < M) {
    float v0 = h2_l[wv * 192 + lane], v1 = h2_l[wv * 192 + lane + 64],
          v2 = h2_l[wv * 192 + lane + 128];
    float s = v0 + v1 + v2, sq = v0 * v0 + v1 * v1 + v2 * v2;
    #pragma unroll
    for (int m = 1; m < 64; m <<= 1) { s += __shfl_xor(s, m); sq += __shfl_xor(sq, m); }
    if (lane == 0) {
      float mu = s * (1.f / 192.f);
      st[wv * 2] = mu;
      st[wv * 2 + 1] = rsqrtf(sq * (1.f / 192.f) - mu * mu + 1e-5f);
    }
  }
  __syncthreads();
  const float* mg = mlng + g * DD;
  const float* mb = mlnb + g * DD;
  float gd = mg[d], bd = mb[d];
  #pragma unroll
  for (int j = 0; j < M; ++j)
    ln_l[j * 192 + d] = (h2_l[j * 192 + d] - st[j * 2]) * st[j * 2 + 1] * gd + bd;
  __syncthreads();
  const float* W1g = W1 + g * DD * HH;
  const float* b1g = b1 + g * HH;
  float a1[4][M];
  #pragma unroll
  for (int c = 0; c < 4; ++c)
    #pragma unroll
    for (int j = 0; j < M; ++j) a1[c][j] = 0.f;
  #pragma unroll 2
  for (int e = 0; e < DD; ++e) {
    float w0 = W1g[e * HH + d];
    float w1 = W1g[e * HH + 192 + d];
    float w2 = W1g[e * HH + 384 + d];
    float w3 = W1g[e * HH + 576 + d];
    #pragma unroll
    for (int j = 0; j < M; ++j) {
      float le = ln_l[j * 192 + e];
      a1[0][j] += w0 * le; a1[1][j] += w1 * le; a1[2][j] += w2 * le; a1[3][j] += w3 * le;
    }
  }
  #pragma unroll
  for (int c = 0; c < 4; ++c) {
    float bc = b1g[c * 192 + d];
    #pragma unroll
    for (int j = 0; j < M; ++j)
      x1_l[j * HH + c * 192 + d] = fmaxf(a1[c][j] + bc, 0.f);
  }
  __syncthreads();
  const float* W2g = W2 + g * HH * DD;
  const float* b2g = b2 + g * DD;
  float a2[M];
  #pragma unroll
  for (int j = 0; j < M; ++j) a2[j] = 0.f;
  #pragma unroll 2
  for (int e = 0; e < HH; ++e) {
    float wv2 = W2g[e * DD + d];
    #pragma unroll
    for (int j = 0; j < M; ++j) a2[j] += wv2 * x1_l[j * HH + e];
  }
  float bd2 = b2g[d];
  #pragma unroll
  for (int j = 0; j < M; ++j)
    sout[(b * 8 + s0f + j) * DD + d] = hnew[j] + a2[j] + bd2;
}

__global__ __launch_bounds__(192) void gru_kernel(
    const float* __restrict__ upd, const float* __restrict__ asum,
    const float* __restrict__ sin_,
    const float* __restrict__ WihT, const float* __restrict__ WhhT,
    const float* __restrict__ bih, const float* __restrict__ bhh,
    const float* __restrict__ mlng, const float* __restrict__ mlnb,
    const float* __restrict__ W1, const float* __restrict__ b1,
    const float* __restrict__ W2, const float* __restrict__ b2,
    float* __restrict__ sout) {
  __shared__ float smem[4616];
  int b = blockIdx.x, y = blockIdx.y;
  if (y == 0)
    gru_body<1>(b, 0, 0, smem, upd, asum, sin_, WihT, WhhT, bih, bhh, mlng, mlnb, W1, b1, W2, b2, sout);
  else if (y == 1)
    gru_body<1>(b, 2, 7, smem, upd, asum, sin_, WihT, WhhT, bih, bhh, mlng, mlnb, W1, b1, W2, b2, sout);
  else if (y == 2)
    gru_body<3>(b, 1, 1, smem, upd, asum, sin_, WihT, WhhT, bih, bhh, mlng, mlnb, W1, b1, W2, b2, sout);
  else
    gru_body<3>(b, 1, 4, smem, upd, asum, sin_, WihT, WhhT, bih, bhh, mlng, mlnb, W1, b1, W2, b2, sout);
}

// ---------------------------------------------------------------------------
extern "C" void kernel_launch(void* const* d_in, const int* in_sizes, int n_in,
                              void* d_out, int out_size, void* d_ws, size_t ws_size,
                              hipStream_t stream) {
  const float* feat = (const float*)d_in[0];
  const float* slots = (const float*)d_in[1];
  const float* Wk = (const float*)d_in[2];
  const float* Wv = (const float*)d_in[3];
  const float* Wq = (const float*)d_in[4];
  const float* lfg = (const float*)d_in[5];
  const float* lfb = (const float*)d_in[6];
  const float* lsg = (const float*)d_in[7];
  const float* lsb = (const float*)d_in[8];
  const float* gWih = (const float*)d_in[9];
  const float* gWhh = (const float*)d_in[10];
  const float* gbih = (const float*)d_in[11];
  const float* gbhh = (const float*)d_in[12];
  const float* mlng = (const float*)d_in[13];
  const float* mlnb = (const float*)d_in[14];
  const float* W1 = (const float*)d_in[15];
  const float* b1 = (const float*)d_in[16];
  const float* W2 = (const float*)d_in[17];
  const float* b2 = (const float*)d_in[18];
  float* out = (float*)d_out;

  char* ws = (char*)d_ws;
  size_t off = 0;
  auto alloc = [&](size_t bytes) {
    void* p = ws + off;
    off += (bytes + 255) & ~(size_t)255;
    return p;
  };
  u16* kbuf   = (u16*)alloc((size_t)BB * FF * DD * 2);
  u16* vT     = (u16*)alloc((size_t)BB * DD * FF * 2);
  u16* attnT  = (u16*)alloc((size_t)BB * 16 * FF * 2);
  float* qbuf = (float*)alloc((size_t)BB * 8 * DD * 4);
  float* upd  = (float*)alloc((size_t)BB * 8 * DD * 4);
  float* slA  = (float*)alloc((size_t)BB * 8 * DD * 4);
  float* slB  = (float*)alloc((size_t)BB * 8 * DD * 4);
  float* asum0 = (float*)alloc(BB * 8 * 4);
  float* asum1 = (float*)alloc(BB * 8 * 4);
  float* cacc0 = (float*)alloc(BB * 8 * 2 * 4);
  float* cacc1 = (float*)alloc(BB * 8 * 2 * 4);
  u16* wmodT  = (u16*)alloc(384 * DD * 2);
  float* s1   = (float*)alloc(384 * 4);
  float* s0   = (float*)alloc(384 * 4);
  float* WihT = (float*)alloc((size_t)3 * DD * 576 * 4);
  float* WhhT = (float*)alloc((size_t)3 * DD * 576 * 4);

  prep_wmod<<<1, 384, 0, stream>>>(Wk, Wv, lfg, lfb, wmodT, s1, s0);
  prep_grut<<<6, 256, 0, stream>>>(gWih, gWhh, WihT, WhhT);
  proj_kernel<<<BB * FF / 128, 512, 0, stream>>>(feat, wmodT, s1, s0, kbuf, vT);

  const float* sin_ = slots;
  float* souts[3] = {slA, slB, out};
  float* asums[2] = {asum0, asum1};
  float* caccs[2] = {cacc0, cacc1};
  for (int it = 0; it < 3; ++it) {
    int cur = it & 1, prev = cur ^ 1;
    hipMemsetAsync(upd, 0, BB * 8 * DD * 4, stream);
    hipMemsetAsync(asums[cur], 0, BB * 8 * 4, stream);
    hipMemsetAsync(caccs[cur], 0, BB * 8 * 2 * 4, stream);
    qproj_kernel<<<BB * 8, 64, 0, stream>>>(sin_, Wq, lsg, lsb, qbuf);
    attn_kernel<<<dim3(BB, 4), 256, 0, stream>>>(kbuf, qbuf, asums[prev], caccs[prev],
                                                 attnT, asums[cur], caccs[cur], it > 0 ? 1 : 0);
    upd_kernel<<<dim3(BB, 12), 256, 0, stream>>>(attnT, vT, upd);
    gru_kernel<<<dim3(BB, 4), 192, 0, stream>>>(upd, asums[cur], sin_, WihT, WhhT,
                                                gbih, gbhh, mlng, mlnb, W1, b1, W2, b2,
                                                souts[it]);
    sin_ = souts[it];
  }
}

// Round 2
// 548.420 us; speedup vs baseline: 2.1332x; 2.1332x over previous
//
#include <hip/hip_runtime.h>

typedef unsigned short u16;
typedef unsigned int u32;

#define BB 64
#define FF 4096
#define DD 192
#define HH 768

typedef __attribute__((ext_vector_type(8))) __bf16 bf16x8;
typedef __attribute__((ext_vector_type(4))) float f32x4;

__device__ __forceinline__ float bf2f(u32 u) {
  union { u32 i; float f; } x; x.i = u << 16; return x.f;
}
__device__ __forceinline__ u16 f2bf(float f) {
  union { u32 i; float f; } x; x.f = f;
  return (u16)((x.i + 0x7fffu + ((x.i >> 16) & 1u)) >> 16);
}
__device__ __forceinline__ float sigm(float x) { return 1.f / (1.f + __expf(-x)); }

// ---------------------------------------------------------------------------
// Prep: WmodT[n][e] = g[e]*W[e][n] (bf16), s1[n]=sum g*W (bf16-rounded), s0[n]=b@W.
// ---------------------------------------------------------------------------
__global__ void prep_wmod(const float* __restrict__ Wk, const float* __restrict__ Wv,
                          const float* __restrict__ g, const float* __restrict__ bb,
                          u16* __restrict__ wmodT, float* __restrict__ s1,
                          float* __restrict__ s0) {
  int n = blockIdx.x * 64 + threadIdx.x;  // 0..383
  const float* W = (n < DD) ? Wk : Wv;
  int col = (n < DD) ? n : n - DD;
  float a1 = 0.f, a0 = 0.f;
  for (int e = 0; e < DD; ++e) {
    float w = W[e * DD + col];
    u16 h = f2bf(g[e] * w);
    wmodT[n * DD + e] = h;
    a1 += bf2f(h);
    a0 += bb[e] * w;
  }
  s1[n] = a1; s0[n] = a0;
}

// Pack GRU/MLP weights to bf16 e-pairs: dst[((g*E2+e/2)*N + n)*2 + (e&1)].
__global__ void prep_packw(const float* __restrict__ Wih, const float* __restrict__ Whh,
                           const float* __restrict__ W1, const float* __restrict__ W2,
                           u16* __restrict__ pWih, u16* __restrict__ pWhh,
                           u16* __restrict__ pW1, u16* __restrict__ pW2) {
  int which = blockIdx.y;
  int total, N, E;
  const float* src; u16* dst; int srcEmajor;
  if (which < 2) { total = 3 * 576 * 192; N = 576; E = 192; srcEmajor = 0;
                   src = which ? Whh : Wih; dst = which ? pWhh : pWih; }
  else if (which == 2) { total = 3 * 192 * 768; N = 768; E = 192; srcEmajor = 1;
                         src = W1; dst = pW1; }
  else { total = 3 * 768 * 192; N = 192; E = 768; srcEmajor = 1; src = W2; dst = pW2; }
  for (int idx = blockIdx.x * 256 + threadIdx.x; idx < total; idx += gridDim.x * 256) {
    int g = idx / (N * E), rem = idx % (N * E);
    int n, e;
    if (srcEmajor) { e = rem / N; n = rem % N; }    // src[g][e][n]
    else { n = rem / E; e = rem % E; }              // src[g][n][e]
    dst[((g * (E / 2) + (e >> 1)) * N + n) * 2 + (e & 1)] = f2bf(src[idx]);
  }
}

// ---------------------------------------------------------------------------
// Projection: k = LN(x)@Wk, v = LN(x)@Wv, LN folded into epilogue.
// kc_: chunked fragment layout [b*256+T][u(24)][tok(16)][8dims] bf16.
// vT : d-major (B,192,F) bf16.
// Block: 512 thr (8 waves), M-tile = 128 tokens, N = 384 (k|v).
// ---------------------------------------------------------------------------
__global__ __launch_bounds__(512) void proj_kernel(
    const float* __restrict__ feat, const u16* __restrict__ wmodT,
    const float* __restrict__ s1, const float* __restrict__ s0,
    u16* __restrict__ kc_, u16* __restrict__ vT) {
  __shared__ __align__(16) u16 Atile[128 * 192];  // swizzled bf16; reused as C tile
  __shared__ float stats[128 * 2];                // (mu, rstd)
  int tid = threadIdx.x;
  long tile_base = (long)blockIdx.x * 128;
  int w = tid >> 6, lane = tid & 63;
  // ---- staging: wave w owns rows w*16..+15; 4 lanes per row, shuffle stats ----
  {
    int r = w * 16 + (lane >> 2);
    int p = lane & 3;
    const float4* src = (const float4*)(feat + (tile_base + r) * DD) + p * 12;
    float s = 0.f, s2 = 0.f;
    #pragma unroll
    for (int i = 0; i < 12; ++i) {
      float4 v = src[i];
      s += v.x + v.y + v.z + v.w;
      s2 += v.x * v.x + v.y * v.y + v.z * v.z + v.w * v.w;
      uint2 pk;
      pk.x = (u32)f2bf(v.x) | ((u32)f2bf(v.y) << 16);
      pk.y = (u32)f2bf(v.z) | ((u32)f2bf(v.w) << 16);
      int u = p * 6 + (i >> 1);
      *(uint2*)((char*)Atile + r * 384 + ((u ^ (r & 7)) << 4) + (i & 1) * 8) = pk;
    }
    s += __shfl_xor(s, 1); s2 += __shfl_xor(s2, 1);
    s += __shfl_xor(s, 2); s2 += __shfl_xor(s2, 2);
    if (p == 0) {
      float mu = s * (1.f / 192.f);
      stats[r * 2] = mu;
      stats[r * 2 + 1] = rsqrtf(s2 * (1.f / 192.f) - mu * mu + 1e-5f);
    }
  }
  __syncthreads();
  // ---- MFMA compute ----
  int mh = w >> 2, nq = w & 3;     // M-half (64 rows), N-quarter (96 cols)
  int l15 = lane & 15, l4 = lane >> 4;
  f32x4 acc[4][6];
  #pragma unroll
  for (int a = 0; a < 4; ++a)
    #pragma unroll
    for (int b2 = 0; b2 < 6; ++b2) acc[a][b2] = (f32x4){0.f, 0.f, 0.f, 0.f};
  #pragma unroll
  for (int kk = 0; kk < 6; ++kk) {
    bf16x8 afr[4];
    #pragma unroll
    for (int mt = 0; mt < 4; ++mt) {
      int row = mh * 64 + mt * 16 + l15;
      int u = kk * 4 + l4;
      afr[mt] = *(bf16x8*)((char*)Atile + row * 384 + ((u ^ (row & 7)) << 4));
    }
    bf16x8 bfr[6];
    #pragma unroll
    for (int nt = 0; nt < 6; ++nt) {
      int col = nq * 96 + nt * 16 + l15;
      bfr[nt] = *(const bf16x8*)(wmodT + col * DD + kk * 32 + l4 * 8);
    }
    #pragma unroll
    for (int mt = 0; mt < 4; ++mt)
      #pragma unroll
      for (int nt = 0; nt < 6; ++nt)
        acc[mt][nt] = __builtin_amdgcn_mfma_f32_16x16x32_bf16(afr[mt], bfr[nt],
                                                              acc[mt][nt], 0, 0, 0);
  }
  // per-token LN stats into regs
  float muv[4][4], rsv[4][4];
  #pragma unroll
  for (int mt = 0; mt < 4; ++mt)
    #pragma unroll
    for (int j = 0; j < 4; ++j) {
      int row = mh * 64 + mt * 16 + l4 * 4 + j;
      muv[mt][j] = stats[row * 2];
      rsv[mt][j] = stats[row * 2 + 1];
    }
  __syncthreads();   // all fragment reads of Atile complete
  // ---- pass 1: k -> Ctile[token][kcol] (swizzled), then chunked coalesced store ----
  if (nq < 2) {
    #pragma unroll
    for (int nt = 0; nt < 6; ++nt) {
      int col = nq * 96 + nt * 16 + l15;
      float s1c = s1[col], s0c = s0[col];
      int u = col >> 3, ce = (col & 7) * 2;
      #pragma unroll
      for (int mt = 0; mt < 4; ++mt) {
        #pragma unroll
        for (int j = 0; j < 4; ++j) {
          int row = mh * 64 + mt * 16 + l4 * 4 + j;
          u16 hv = f2bf(rsv[mt][j] * (acc[mt][nt][j] - muv[mt][j] * s1c) + s0c);
          *(u16*)((char*)Atile + row * 384 + ((u ^ (row & 7)) << 4) + ce) = hv;
        }
      }
    }
  }
  __syncthreads();
  {
    long Tg0 = tile_base >> 4;
    #pragma unroll
    for (int p2 = 0; p2 < 6; ++p2) {
      int fi = tid + p2 * 512;
      int tau = fi & 15, u = (fi >> 4) % 24, tt = fi / 384;
      uint4 val = *(uint4*)((char*)Atile + (tt * 16 + tau) * 384 + ((u ^ (tau & 7)) << 4));
      *(uint4*)(kc_ + (((Tg0 + tt) * 24 + u) * 16 + tau) * 8) = val;
    }
  }
  __syncthreads();
  // ---- pass 2: v -> CtileV[vcol][token] (swizzled), then d-major coalesced store ----
  if (nq >= 2) {
    #pragma unroll
    for (int nt = 0; nt < 6; ++nt) {
      int col = nq * 96 + nt * 16 + l15;      // 192..383
      float s1c = s1[col], s0c = s0[col];
      int vcol = col - 192;
      #pragma unroll
      for (int mt = 0; mt < 4; ++mt) {
        int tok0 = mh * 64 + mt * 16 + l4 * 4;
        u16 h[4];
        #pragma unroll
        for (int j = 0; j < 4; ++j)
          h[j] = f2bf(rsv[mt][j] * (acc[mt][nt][j] - muv[mt][j] * s1c) + s0c);
        uint2 pk;
        pk.x = (u32)h[0] | ((u32)h[1] << 16);
        pk.y = (u32)h[2] | ((u32)h[3] << 16);
        *(uint2*)((char*)Atile + vcol * 256 + (((tok0 >> 3) ^ (vcol & 7)) << 4) +
                  (tok0 & 7) * 2) = pk;
      }
    }
  }
  __syncthreads();
  {
    long bidx = tile_base / FF;
    int f0 = (int)(tile_base % FF);
    #pragma unroll
    for (int p2 = 0; p2 < 6; ++p2) {
      int fi = tid + p2 * 512;
      int d = fi >> 4, tc = fi & 15;
      uint4 val = *(uint4*)((char*)Atile + d * 256 + ((tc ^ (d & 7)) << 4));
      *(uint4*)(vT + (bidx * 192 + d) * FF + f0 + tc * 8) = val;
    }
  }
}

// ---------------------------------------------------------------------------
// q projection: q = LN(slots) @ Wq * scale.  One wave per (b,k).
// ---------------------------------------------------------------------------
__global__ __launch_bounds__(64) void qproj_kernel(
    const float* __restrict__ slots, const float* __restrict__ Wq,
    const float* __restrict__ g, const float* __restrict__ bb,
    float* __restrict__ qbuf) {
  __shared__ float ln[192];
  int bk = blockIdx.x;
  int lane = threadIdx.x;
  const float* x = slots + bk * DD;
  float v0 = x[lane], v1 = x[lane + 64], v2 = x[lane + 128];
  float s = v0 + v1 + v2, s2 = v0 * v0 + v1 * v1 + v2 * v2;
  #pragma unroll
  for (int m = 1; m < 64; m <<= 1) { s += __shfl_xor(s, m); s2 += __shfl_xor(s2, m); }
  float mu = s * (1.f / 192.f);
  float rstd = rsqrtf(s2 * (1.f / 192.f) - mu * mu + 1e-5f);
  ln[lane]       = (v0 - mu) * rstd * g[lane]       + bb[lane];
  ln[lane + 64]  = (v1 - mu) * rstd * g[lane + 64]  + bb[lane + 64];
  ln[lane + 128] = (v2 - mu) * rstd * g[lane + 128] + bb[lane + 128];
  __syncthreads();
  float a0 = 0.f, a1 = 0.f, a2 = 0.f;
  for (int e = 0; e < DD; ++e) {
    float le = ln[e];
    a0 += le * Wq[e * DD + lane];
    a1 += le * Wq[e * DD + lane + 64];
    a2 += le * Wq[e * DD + lane + 128];
  }
  const float scale = 0.07216878364870323f;  // 192^-0.5
  qbuf[bk * DD + lane]       = a0 * scale;
  qbuf[bk * DD + lane + 64]  = a1 * scale;
  qbuf[bk * DD + lane + 128] = a2 * scale;
}

// ---------------------------------------------------------------------------
// Attention: dots = q@k^T (+ spatial bias), softmax over 8 slots, store attn
// (slot-major bf16), accumulate attn sums + coord moments.
// grid (B, 16): 256 tokens per block.  k read from chunked layout (coalesced).
// ---------------------------------------------------------------------------
__global__ __launch_bounds__(256) void attn_kernel(
    const u16* __restrict__ kc_, const float* __restrict__ qbuf,
    const float* __restrict__ asum_prev, const float* __restrict__ cacc_prev,
    u16* __restrict__ attnT, float* __restrict__ asum_cur,
    float* __restrict__ cacc_cur, int have_bias) {
  __shared__ __align__(16) u16 qlds[16 * 192];
  int b = blockIdx.x;
  int chunk = blockIdx.y * 256;
  int tid = threadIdx.x;
  if (tid < 192) {
    int s = tid / 24, u = tid % 24;
    const float* qp = qbuf + (b * 8 + s) * DD + u * 8;
    uint4 p;
    p.x = (u32)f2bf(qp[0]) | ((u32)f2bf(qp[1]) << 16);
    p.y = (u32)f2bf(qp[2]) | ((u32)f2bf(qp[3]) << 16);
    p.z = (u32)f2bf(qp[4]) | ((u32)f2bf(qp[5]) << 16);
    p.w = (u32)f2bf(qp[6]) | ((u32)f2bf(qp[7]) << 16);
    *(uint4*)((char*)qlds + s * 384 + ((u ^ (s & 7)) << 4)) = p;
  } else {
    int t2 = tid - 192;
    #pragma unroll
    for (int i = 0; i < 3; ++i) {
      int idx = t2 * 3 + i;      // 192 units of rows 8..15
      int s = 8 + idx / 24, u = idx % 24;
      *(uint4*)((char*)qlds + s * 384 + ((u ^ (s & 7)) << 4)) = (uint4){0, 0, 0, 0};
    }
  }
  __syncthreads();
  int w = tid >> 6, lane = tid & 63;
  int l15 = lane & 15, l4 = lane >> 4;
  bf16x8 qfr[6];
  #pragma unroll
  for (int kk = 0; kk < 6; ++kk) {
    int u = kk * 4 + l4;
    qfr[kk] = *(bf16x8*)((char*)qlds + l15 * 384 + ((u ^ (l15 & 7)) << 4));
  }
  float ax[4], ay[4], c0[4];
  #pragma unroll
  for (int j = 0; j < 4; ++j) {
    int s = l4 * 4 + j;
    if (have_bias && s < 8) {
      float inv = 1.f / (asum_prev[b * 8 + s] + 1e-8f);
      float cx = cacc_prev[(b * 8 + s) * 2] * inv;
      float cy = cacc_prev[(b * 8 + s) * 2 + 1] * inv;
      ax[j] = 16.f * cx; ay[j] = 16.f * cy; c0[j] = -8.f * (cx * cx + cy * cy);
    } else { ax[j] = 0.f; ay[j] = 0.f; c0[j] = 0.f; }
  }
  float pa[4], px[4], py[4];
  #pragma unroll
  for (int j = 0; j < 4; ++j) { pa[j] = 0.f; px[j] = 0.f; py[j] = 0.f; }
  for (int tile = w; tile < 16; tile += 4) {
    int t0 = chunk + tile * 16;
    long Tg = (long)b * 256 + (t0 >> 4);
    const u16* kp = kc_ + (Tg * 24 + l4) * 128 + l15 * 8;
    f32x4 acc = (f32x4){0.f, 0.f, 0.f, 0.f};
    #pragma unroll
    for (int kk = 0; kk < 6; ++kk) {
      bf16x8 bfr = *(const bf16x8*)(kp + kk * 512);
      acc = __builtin_amdgcn_mfma_f32_16x16x32_bf16(qfr[kk], bfr, acc, 0, 0, 0);
    }
    int t = t0 + l15;
    float x = -1.f + (float)(t & 63) * (2.f / 63.f);
    float y = -1.f + (float)(t >> 6) * (2.f / 63.f);
    float m8r2 = -8.f * (x * x + y * y);
    float d4[4];
    #pragma unroll
    for (int j = 0; j < 4; ++j)
      d4[j] = acc[j] + (have_bias ? (ax[j] * x + ay[j] * y + c0[j] + m8r2) : 0.f);
    float o4[4];
    #pragma unroll
    for (int j = 0; j < 4; ++j) o4[j] = __shfl_xor(d4[j], 16);
    float mx = fmaxf(fmaxf(fmaxf(d4[0], d4[1]), fmaxf(d4[2], d4[3])),
                     fmaxf(fmaxf(o4[0], o4[1]), fmaxf(o4[2], o4[3])));
    float e4[4];
    float sum = 0.f;
    #pragma unroll
    for (int j = 0; j < 4; ++j) { e4[j] = __expf(d4[j] - mx); sum += e4[j]; }
    #pragma unroll
    for (int j = 0; j < 4; ++j) sum += __expf(o4[j] - mx);
    float inv = 1.f / sum;
    if (l4 < 2) {
      #pragma unroll
      for (int j = 0; j < 4; ++j) {
        float a = e4[j] * inv;
        attnT[((long)(b * 16) + l4 * 4 + j) * FF + t] = f2bf(a);
        pa[j] += a; px[j] += a * x; py[j] += a * y;
      }
    }
  }
  #pragma unroll
  for (int m = 1; m < 16; m <<= 1) {
    #pragma unroll
    for (int j = 0; j < 4; ++j) {
      pa[j] += __shfl_xor(pa[j], m);
      px[j] += __shfl_xor(px[j], m);
      py[j] += __shfl_xor(py[j], m);
    }
  }
  if (l15 == 0 && l4 < 2) {
    #pragma unroll
    for (int j = 0; j < 4; ++j) {
      int s = l4 * 4 + j;
      atomicAdd(&asum_cur[b * 8 + s], pa[j]);
      atomicAdd(&cacc_cur[(b * 8 + s) * 2], px[j]);
      atomicAdd(&cacc_cur[(b * 8 + s) * 2 + 1], py[j]);
    }
  }
}

// ---------------------------------------------------------------------------
// updates (unnormalized) = attn @ v.  grid (B, 12 n-tiles), 4 waves = K-chunks,
// cross-wave LDS reduce, plain store (no global atomics, no pre-zero).
// ---------------------------------------------------------------------------
__global__ __launch_bounds__(256) void upd_kernel(
    const u16* __restrict__ attnT, const u16* __restrict__ vT,
    float* __restrict__ upd) {
  __shared__ float red[4][8][16];
  int b = blockIdx.x, nt = blockIdx.y;
  int tid = threadIdx.x;
  int w = tid >> 6, lane = tid & 63;
  int l15 = lane & 15, l4 = lane >> 4;
  int kc = w * 1024;
  const u16* ap = attnT + ((long)(b * 16) + l15) * FF + kc + l4 * 8;
  const u16* vp = vT + ((long)b * 192 + nt * 16 + l15) * FF + kc + l4 * 8;
  f32x4 acc = (f32x4){0.f, 0.f, 0.f, 0.f};
  #pragma unroll 4
  for (int ks = 0; ks < 32; ++ks) {
    bf16x8 afr = *(const bf16x8*)(ap + ks * 32);
    bf16x8 bfr = *(const bf16x8*)(vp + ks * 32);
    acc = __builtin_amdgcn_mfma_f32_16x16x32_bf16(afr, bfr, acc, 0, 0, 0);
  }
  if (l4 < 2) {
    #pragma unroll
    for (int j = 0; j < 4; ++j) red[w][l4 * 4 + j][l15] = acc[j];
  }
  __syncthreads();
  if (tid < 128) {
    int s = tid >> 4, l = tid & 15;
    float t = red[0][s][l] + red[1][s][l] + red[2][s][l] + red[3][s][l];
    upd[((long)b * 8 + s) * DD + nt * 16 + l] = t;
  }
}

// ---------------------------------------------------------------------------
// GRU + LN + MLP.  768 threads (12 waves), column-parallel phases, bf16 weights.
// grid (B, 4): y0: g0 slot0 (M=1); y1: g2 slot7 (M=1); y2: g1 slots1-3; y3: g1 slots4-6.
// ---------------------------------------------------------------------------
template <int M>
__device__ void gru_body(int b0, int g, int srow,
                         float* u_l, float* h_l, float* gi_l, float* gh_l,
                         float* hn_l, float* ln_l, float* x1_l, float* out_l, float* st,
                         const float* __restrict__ upd, const float* __restrict__ asum,
                         const float* __restrict__ sin_,
                         const u16* __restrict__ pWih, const u16* __restrict__ pWhh,
                         const float* __restrict__ bih, const float* __restrict__ bhh,
                         const float* __restrict__ mlng, const float* __restrict__ mlnb,
                         const u16* __restrict__ pW1, const float* __restrict__ b1,
                         const u16* __restrict__ pW2, const float* __restrict__ b2,
                         float* __restrict__ sout) {
  int tid = threadIdx.x;
  for (int idx = tid; idx < M * 192; idx += 768) {
    int row = idx / 192, d = idx % 192;
    int gr = b0 * 8 + srow + row;
    float inv = 1.f / (asum[gr] + 1e-8f);
    u_l[row * 192 + d] = upd[gr * DD + d] * inv;
    h_l[row * 192 + d] = sin_[gr * DD + d];
  }
  __syncthreads();
  // GRU gates: thread = output col c of [r|z|n]x192
  if (tid < 576) {
    int c = tid;
    const u16* wih = pWih + (size_t)g * 96 * 1152 + c * 2;
    const u16* whh = pWhh + (size_t)g * 96 * 1152 + c * 2;
    float ai[M], ah[M];
    #pragma unroll
    for (int r = 0; r < M; ++r) { ai[r] = 0.f; ah[r] = 0.f; }
    #pragma unroll 4
    for (int e2 = 0; e2 < 96; ++e2) {
      u32 wi = *(const u32*)(wih + e2 * 1152);
      u32 wh = *(const u32*)(whh + e2 * 1152);
      float wi0 = bf2f(wi & 0xffffu), wi1 = bf2f(wi >> 16);
      float wh0 = bf2f(wh & 0xffffu), wh1 = bf2f(wh >> 16);
      #pragma unroll
      for (int r = 0; r < M; ++r) {
        ai[r] += wi0 * u_l[r * 192 + e2 * 2] + wi1 * u_l[r * 192 + e2 * 2 + 1];
        ah[r] += wh0 * h_l[r * 192 + e2 * 2] + wh1 * h_l[r * 192 + e2 * 2 + 1];
      }
    }
    #pragma unroll
    for (int r = 0; r < M; ++r) { gi_l[r * 576 + c] = ai[r]; gh_l[r * 576 + c] = ah[r]; }
  }
  __syncthreads();
  // gate math
  if (tid < M * 192) {
    int row = tid / 192, uu = tid % 192;
    const float* bihg = bih + g * 576;
    const float* bhhg = bhh + g * 576;
    float r_ = sigm(gi_l[row * 576 + uu] + bihg[uu] + gh_l[row * 576 + uu] + bhhg[uu]);
    float z_ = sigm(gi_l[row * 576 + 192 + uu] + bihg[192 + uu] +
                    gh_l[row * 576 + 192 + uu] + bhhg[192 + uu]);
    float nn = gi_l[row * 576 + 384 + uu] + bihg[384 + uu] +
               r_ * (gh_l[row * 576 + 384 + uu] + bhhg[384 + uu]);
    float t = 1.f - 2.f / (__expf(2.f * nn) + 1.f);
    hn_l[row * 192 + uu] = (1.f - z_) * t + z_ * h_l[row * 192 + uu];
  }
  __syncthreads();
  // LN stats: wave per row
  {
    int wv = tid >> 6, lane = tid & 63;
    if (wv < M) {
      float v0 = hn_l[wv * 192 + lane], v1 = hn_l[wv * 192 + lane + 64],
            v2 = hn_l[wv * 192 + lane + 128];
      float s = v0 + v1 + v2, sq = v0 * v0 + v1 * v1 + v2 * v2;
      #pragma unroll
      for (int m = 1; m < 64; m <<= 1) { s += __shfl_xor(s, m); sq += __shfl_xor(sq, m); }
      if (lane == 0) {
        float mu = s * (1.f / 192.f);
        st[wv * 2] = mu;
        st[wv * 2 + 1] = rsqrtf(sq * (1.f / 192.f) - mu * mu + 1e-5f);
      }
    }
  }
  __syncthreads();
  if (tid < M * 192) {
    int row = tid / 192, uu = tid % 192;
    ln_l[row * 192 + uu] = (hn_l[row * 192 + uu] - st[row * 2]) * st[row * 2 + 1] *
                               mlng[g * DD + uu] + mlnb[g * DD + uu];
  }
  __syncthreads();
  // MLP1: thread = col c of 768
  {
    int c = tid;
    const u16* w1 = pW1 + (size_t)g * 96 * 1536 + c * 2;
    float a[M];
    #pragma unroll
    for (int r = 0; r < M; ++r) a[r] = 0.f;
    #pragma unroll 4
    for (int e2 = 0; e2 < 96; ++e2) {
      u32 wp = *(const u32*)(w1 + e2 * 1536);
      float w0 = bf2f(wp & 0xffffu), w1f = bf2f(wp >> 16);
      #pragma unroll
      for (int r = 0; r < M; ++r)
        a[r] += w0 * ln_l[r * 192 + e2 * 2] + w1f * ln_l[r * 192 + e2 * 2 + 1];
    }
    float bc = b1[g * HH + c];
    #pragma unroll
    for (int r = 0; r < M; ++r) x1_l[r * 768 + c] = fmaxf(a[r] + bc, 0.f);
  }
  if (tid < M * 192) {
    int row = tid / 192, uu = tid % 192;
    out_l[row * 192 + uu] = hn_l[row * 192 + uu] + b2[g * DD + uu];
  }
  __syncthreads();
  // MLP2: thread = (col c of 192, K-quarter ks)
  {
    int c = tid % 192, ks = tid / 192;
    const u16* w2 = pW2 + (size_t)g * 384 * 384 + c * 2;
    float a[M];
    #pragma unroll
    for (int r = 0; r < M; ++r) a[r] = 0.f;
    #pragma unroll 4
    for (int e2 = ks * 96; e2 < ks * 96 + 96; ++e2) {
      u32 wp = *(const u32*)(w2 + e2 * 384);
      float w0 = bf2f(wp & 0xffffu), w1f = bf2f(wp >> 16);
      #pragma unroll
      for (int r = 0; r < M; ++r)
        a[r] += w0 * x1_l[r * 768 + e2 * 2] + w1f * x1_l[r * 768 + e2 * 2 + 1];
    }
    #pragma unroll
    for (int r = 0; r < M; ++r) atomicAdd(&out_l[r * 192 + c], a[r]);
  }
  __syncthreads();
  if (tid < M * 192) {
    int row = tid / 192, d = tid % 192;
    sout[(b0 * 8 + srow + row) * DD + d] = out_l[row * 192 + d];
  }
}

__global__ __launch_bounds__(768) void gru_kernel(
    const float* __restrict__ upd, const float* __restrict__ asum,
    const float* __restrict__ sin_,
    const u16* __restrict__ pWih, const u16* __restrict__ pWhh,
    const float* __restrict__ bih, const float* __restrict__ bhh,
    const float* __restrict__ mlng, const float* __restrict__ mlnb,
    const u16* __restrict__ pW1, const float* __restrict__ b1,
    const u16* __restrict__ pW2, const float* __restrict__ b2,
    float* __restrict__ sout) {
  __shared__ float u_l[3 * 192], h_l[3 * 192], gi_l[3 * 576], gh_l[3 * 576];
  __shared__ float hn_l[3 * 192], ln_l[3 * 192], x1_l[3 * 768], out_l[3 * 192], st[8];
  int b = blockIdx.x, y = blockIdx.y;
  if (y == 0)
    gru_body<1>(b, 0, 0, u_l, h_l, gi_l, gh_l, hn_l, ln_l, x1_l, out_l, st,
                upd, asum, sin_, pWih, pWhh, bih, bhh, mlng, mlnb, pW1, b1, pW2, b2, sout);
  else if (y == 1)
    gru_body<1>(b, 2, 7, u_l, h_l, gi_l, gh_l, hn_l, ln_l, x1_l, out_l, st,
                upd, asum, sin_, pWih, pWhh, bih, bhh, mlng, mlnb, pW1, b1, pW2, b2, sout);
  else if (y == 2)
    gru_body<3>(b, 1, 1, u_l, h_l, gi_l, gh_l, hn_l, ln_l, x1_l, out_l, st,
                upd, asum, sin_, pWih, pWhh, bih, bhh, mlng, mlnb, pW1, b1, pW2, b2, sout);
  else
    gru_body<3>(b, 1, 4, u_l, h_l, gi_l, gh_l, hn_l, ln_l, x1_l, out_l, st,
                upd, asum, sin_, pWih, pWhh, bih, bhh, mlng, mlnb, pW1, b1, pW2, b2, sout);
}

// ---------------------------------------------------------------------------
extern "C" void kernel_launch(void* const* d_in, const int* in_sizes, int n_in,
                              void* d_out, int out_size, void* d_ws, size_t ws_size,
                              hipStream_t stream) {
  const float* feat = (const float*)d_in[0];
  const float* slots = (const float*)d_in[1];
  const float* Wk = (const float*)d_in[2];
  const float* Wv = (const float*)d_in[3];
  const float* Wq = (const float*)d_in[4];
  const float* lfg = (const float*)d_in[5];
  const float* lfb = (const float*)d_in[6];
  const float* lsg = (const float*)d_in[7];
  const float* lsb = (const float*)d_in[8];
  const float* gWih = (const float*)d_in[9];
  const float* gWhh = (const float*)d_in[10];
  const float* gbih = (const float*)d_in[11];
  const float* gbhh = (const float*)d_in[12];
  const float* mlng = (const float*)d_in[13];
  const float* mlnb = (const float*)d_in[14];
  const float* W1 = (const float*)d_in[15];
  const float* b1 = (const float*)d_in[16];
  const float* W2 = (const float*)d_in[17];
  const float* b2 = (const float*)d_in[18];
  float* out = (float*)d_out;

  char* ws = (char*)d_ws;
  size_t off = 0;
  auto alloc = [&](size_t bytes) {
    void* p = ws + off;
    off += (bytes + 255) & ~(size_t)255;
    return p;
  };
  u16* kc_    = (u16*)alloc((size_t)BB * FF * DD * 2);
  u16* vT     = (u16*)alloc((size_t)BB * DD * FF * 2);
  u16* attnT  = (u16*)alloc((size_t)BB * 16 * FF * 2);
  float* qbuf = (float*)alloc((size_t)BB * 8 * DD * 4);
  float* upd  = (float*)alloc((size_t)BB * 8 * DD * 4);
  float* slA  = (float*)alloc((size_t)BB * 8 * DD * 4);
  float* slB  = (float*)alloc((size_t)BB * 8 * DD * 4);
  float* asum0 = (float*)alloc(BB * 8 * 4);
  float* asum1 = (float*)alloc(BB * 8 * 4);
  float* cacc0 = (float*)alloc(BB * 8 * 2 * 4);
  float* cacc1 = (float*)alloc(BB * 8 * 2 * 4);
  u16* wmodT  = (u16*)alloc(384 * DD * 2);
  float* s1   = (float*)alloc(384 * 4);
  float* s0   = (float*)alloc(384 * 4);
  u16* pWih   = (u16*)alloc((size_t)3 * 576 * DD * 2);
  u16* pWhh   = (u16*)alloc((size_t)3 * 576 * DD * 2);
  u16* pW1    = (u16*)alloc((size_t)3 * DD * HH * 2);
  u16* pW2    = (u16*)alloc((size_t)3 * HH * DD * 2);

  prep_wmod<<<6, 64, 0, stream>>>(Wk, Wv, lfg, lfb, wmodT, s1, s0);
  prep_packw<<<dim3(432, 4), 256, 0, stream>>>(gWih, gWhh, W1, W2, pWih, pWhh, pW1, pW2);
  proj_kernel<<<BB * FF / 128, 512, 0, stream>>>(feat, wmodT, s1, s0, kc_, vT);

  const float* sin_ = slots;
  float* souts[3] = {slA, slB, out};
  float* asums[2] = {asum0, asum1};
  float* caccs[2] = {cacc0, cacc1};
  for (int it = 0; it < 3; ++it) {
    int cur = it & 1, prev = cur ^ 1;
    hipMemsetAsync(asums[cur], 0, BB * 8 * 4, stream);
    hipMemsetAsync(caccs[cur], 0, BB * 8 * 2 * 4, stream);
    qproj_kernel<<<BB * 8, 64, 0, stream>>>(sin_, Wq, lsg, lsb, qbuf);
    attn_kernel<<<dim3(BB, 16), 256, 0, stream>>>(kc_, qbuf, asums[prev], caccs[prev],
                                                  attnT, asums[cur], caccs[cur], it > 0 ? 1 : 0);
    upd_kernel<<<dim3(BB, 12), 256, 0, stream>>>(attnT, vT, upd);
    gru_kernel<<<dim3(BB, 4), 768, 0, stream>>>(upd, asums[cur], sin_, pWih, pWhh,
                                                gbih, gbhh, mlng, mlnb, pW1, b1, pW2, b2,
                                                souts[it]);
    sin_ = souts[it];
  }
}